// Round 4
// baseline (301.331 us; speedup 1.0000x reference)
//
#include <hip/hip_runtime.h>

// x: [B=2, C=3, D=128, H=160, W=160] fp32, num_steps=6
#define BB 2
#define DD 128
#define HH 160
#define WW 160
constexpr int S   = DD * HH * WW;    // voxels per batch   = 3,276,800
constexpr int PL  = HH * WW;         // plane (h*w)        = 25,600
constexpr int K   = 4;               // voxels per thread
constexpr int VPB = 256 * K;         // 1024 voxels per block
constexpr int TPP = PL / VPB;        // 25 tiles per plane
constexpr int NT  = BB * DD * TPP;   // 6400 blocks
constexpr int PER_XCD = NT / 8;      // 800 -> 32 contiguous d-planes per XCD

// 12-byte, 4-aligned record: single dwordx3 load/store
struct __attribute__((packed, aligned(4))) f3 { float x, y, z; };

// clamp(round(base + flow)) per dim; returns clamped coords + linear index
__device__ __forceinline__ void clamp_idx(int d, int h, int w,
                                          float f0, float f1, float f2,
                                          int& od, int& oh, int& ow, int& lin) {
    od = (int)fminf(fmaxf(rintf((float)d + f0), 0.0f), (float)(DD - 1));
    oh = (int)fminf(fmaxf(rintf((float)h + f1), 0.0f), (float)(HH - 1));
    ow = (int)fminf(fmaxf(rintf((float)w + f2), 0.0f), (float)(WW - 1));
    lin = (od * HH + oh) * WW + ow;
}

template <bool SOA>
__device__ __forceinline__ void load3(const float* __restrict__ v, int b, int idx,
                                      float scale, float* o) {
    if constexpr (SOA) {
        int s = b * 3 * S + idx;
        o[0] = v[s] * scale; o[1] = v[s + S] * scale; o[2] = v[s + 2 * S] * scale;
    } else {
        f3 t = *(const f3*)(v + (b * S + idx) * 3);
        o[0] = t.x; o[1] = t.y; o[2] = t.z;
    }
}

// v_N(q) = v_{N-1}(q) + v_{N-1}(r),  r = clamp(round(q + v_{N-1}(q))).
// Matches the reference's addition tree exactly at every level (bit-exact).
// v0q = base-field value at q, already in registers.
// Gather sites at recursion level N <= MASKN are exec-masked on index identity
// (r == q  =>  reuse v0q, no load issued). Mask only pays where the jump
// displacement sigma <= 0.5 voxel (wave/quad-level skips); above that the
// branch is pure overhead, so it is compiled out.
template <int N, int MASKN, bool SOA>
__device__ __forceinline__ void eval(const float* __restrict__ vin, int b, float scale,
                                     int qd, int qh, int qw, int qi,
                                     const float* v0q, float* out) {
    if constexpr (N == 0) {
        out[0] = v0q[0]; out[1] = v0q[1]; out[2] = v0q[2];
    } else {
        float a[3];                       // a = v_{N-1}(q)
        eval<N - 1, MASKN, SOA>(vin, b, scale, qd, qh, qw, qi, v0q, a);
        int rd, rh, rw, ri;               // r = clamp(round(q + a))
        clamp_idx(qd, qh, qw, a[0], a[1], a[2], rd, rh, rw, ri);
        float v0r[3];                     // base field at r
        if constexpr (N <= MASKN) {
            if (ri != qi) {
                load3<SOA>(vin, b, ri, scale, v0r);
            } else {
                v0r[0] = v0q[0]; v0r[1] = v0q[1]; v0r[2] = v0q[2];
            }
        } else {
            load3<SOA>(vin, b, ri, scale, v0r);
        }
        float g[3];                       // g = v_{N-1}(r)
        eval<N - 1, MASKN, SOA>(vin, b, scale, rd, rh, rw, ri, v0r, g);
        out[0] = a[0] + g[0];
        out[1] = a[1] + g[1];
        out[2] = a[2] + g[2];
    }
}

// NSTEP squaring steps fused. IN_SOA: read [3,S] (input x, fused /64 scale).
// OUT_SOA: write [3,S] (final out). Otherwise tight 12 B AoS [S,3].
template <int NSTEP, int MASKN, bool IN_SOA, bool OUT_SOA>
__global__ __launch_bounds__(256) void squash_k(const float* __restrict__ vin,
                                                float* __restrict__ vout,
                                                float scale) {
    // XCD-aware swizzle: each XCD owns a contiguous 1/8 slab (32 d-planes).
    int t  = blockIdx.x;
    int nb = (t >> 3) + (t & 7) * PER_XCD;
    int b  = nb / (DD * TPP);
    int r  = nb - b * (DD * TPP);
    int d  = r / TPP;
    int ip0 = (r - d * TPP) * VPB + threadIdx.x;

    int   p[K], h[K], w[K];
    float a0[K][3];
    // K center reads (coalesced), back-to-back
#pragma unroll
    for (int k = 0; k < K; ++k) {
        int ip = ip0 + k * 256;
        w[k] = ip % WW; h[k] = ip / WW;
        p[k] = d * PL + ip;
        load3<IN_SOA>(vin, b, p[k], scale, a0[k]);
    }
    // K independent evaluation trees (TA-throughput-bound; TLP hides latency)
    float o[K][3];
#pragma unroll
    for (int k = 0; k < K; ++k)
        eval<NSTEP, MASKN, IN_SOA>(vin, b, scale, d, h[k], w[k], p[k], a0[k], o[k]);
    // K stores
#pragma unroll
    for (int k = 0; k < K; ++k) {
        if constexpr (OUT_SOA) {
            int s = b * 3 * S + p[k];
            vout[s] = o[k][0]; vout[s + S] = o[k][1]; vout[s + 2 * S] = o[k][2];
        } else {
            f3 v{o[k][0], o[k][1], o[k][2]};
            *(f3*)(vout + (b * S + p[k]) * 3) = v;
        }
    }
}

extern "C" void kernel_launch(void* const* d_in, const int* in_sizes, int n_in,
                              void* d_out, int out_size, void* d_ws, size_t ws_size,
                              hipStream_t stream) {
    const float* x = (const float*)d_in[0];
    float* out = (float*)d_out;     // 78,643,200 bytes — final SoA result
    float* ws  = (float*)d_ws;      // >= 78,643,200 bytes (tight AoS intermediate)

    // Schedule {4,2}: steps 1-4 fused (sigma 0.125..1 — masked sites at levels
    // with sigma<=0.5, i.e. N<=3), then steps 5-6 fused (sigma 2..4 — no masks).
    squash_k<4, 3, true,  false><<<NT, 256, 0, stream>>>(x,  ws,  1.0f / 64.0f);
    squash_k<2, 0, false, true ><<<NT, 256, 0, stream>>>(ws, out, 1.0f);
}

// Round 5
// 256.769 us; speedup vs baseline: 1.1735x; 1.1735x over previous
//
#include <hip/hip_runtime.h>

// x: [B=2, C=3, D=128, H=160, W=160] fp32, num_steps=6
#define BB 2
#define DD 128
#define HH 160
#define WW 160
constexpr int S   = DD * HH * WW;    // voxels per batch   = 3,276,800
constexpr int PL  = HH * WW;         // plane (h*w)        = 25,600
constexpr int K   = 4;               // voxels per thread (4 independent gather chains)
constexpr int VPB = 256 * K;         // 1024 voxels per block
constexpr int TPP = PL / VPB;        // 25 tiles per plane
constexpr int NT  = BB * DD * TPP;   // 6400 blocks
constexpr int PER_XCD = NT / 8;      // 800 -> 32 contiguous d-planes per XCD

// Cost model (fit across rounds 0-4): kernel time ≈ issued-vmem-bytes / 10.5 B/cyc/CU,
// + ~0.8 µs per mask branch. A masked gather site only pays off when the ENTIRE
// wave is identity (s_cbranch_execz skip): P≈0.99 at sigma=0.125, ~0 at sigma>=0.25.
// => {2,2,2} schedule, masks ONLY on the two sigma=0.125 sites of kernel 1.

// 12-byte, 4-aligned record: single dwordx3 load/store
struct __attribute__((packed, aligned(4))) f3 { float x, y, z; };

// clamp(round(base + flow)) per dim; returns clamped coords + linear index
__device__ __forceinline__ void clamp_idx(int d, int h, int w,
                                          float f0, float f1, float f2,
                                          int& od, int& oh, int& ow, int& lin) {
    od = (int)fminf(fmaxf(rintf((float)d + f0), 0.0f), (float)(DD - 1));
    oh = (int)fminf(fmaxf(rintf((float)h + f1), 0.0f), (float)(HH - 1));
    ow = (int)fminf(fmaxf(rintf((float)w + f2), 0.0f), (float)(WW - 1));
    lin = (od * HH + oh) * WW + ow;
}

template <bool SOA>
__device__ __forceinline__ void load3(const float* __restrict__ v, int b, int idx,
                                      float scale, float* o) {
    if constexpr (SOA) {
        int s = b * 3 * S + idx;
        o[0] = v[s] * scale; o[1] = v[s + S] * scale; o[2] = v[s + 2 * S] * scale;
    } else {
        f3 t = *(const f3*)(v + (b * S + idx) * 3);
        o[0] = t.x; o[1] = t.y; o[2] = t.z;
    }
}

// TWO squaring steps fused:  v''(p) = v'(p) + v'(r1),  v'(q) = v(q) + v(r).
// Sites: r0 = round(p + v(p))        jump by v   (sigma_base)
//        r1 = round(p + v'(p))       jump by v'  (2*sigma_base)
//        r2 = round(r1 + v(r1))      jump by v   (sigma_base)
// M0/M2 mask the two sigma_base sites (wave-skippable when sigma_base=0.125);
// r1's site is never wave-skippable for any kernel in this problem -> unmasked.
template <bool IN_SOA, bool OUT_SOA, bool M0, bool M2>
__global__ __launch_bounds__(256) void fused2_k(const float* __restrict__ vin,
                                                float* __restrict__ vout,
                                                float scale) {
    // XCD-aware swizzle: each XCD owns a contiguous 1/8 slab (32 d-planes).
    int t  = blockIdx.x;
    int nb = (t >> 3) + (t & 7) * PER_XCD;
    int b  = nb / (DD * TPP);
    int r  = nb - b * (DD * TPP);
    int d  = r / TPP;
    int ip0 = (r - d * TPP) * VPB + threadIdx.x;

    int   p[K], h[K], w[K];
    float a[K][3];
    // --- stage 1: K center reads (coalesced), back-to-back ---
#pragma unroll
    for (int k = 0; k < K; ++k) {
        int ip = ip0 + k * 256;
        w[k] = ip % WW; h[k] = ip / WW;
        p[k] = d * PL + ip;
        load3<IN_SOA>(vin, b, p[k], scale, a[k]);
    }
    // --- stage 2: r0 = clamp(round(p + v(p))) ; g = v(r0) ---
    int r0i[K];
#pragma unroll
    for (int k = 0; k < K; ++k) {
        int rd, rh, rw;
        clamp_idx(d, h[k], w[k], a[k][0], a[k][1], a[k][2], rd, rh, rw, r0i[k]);
    }
    float g[K][3];
#pragma unroll
    for (int k = 0; k < K; ++k) {
        if constexpr (M0) {
            if (r0i[k] != p[k]) {
                load3<IN_SOA>(vin, b, r0i[k], scale, g[k]);
            } else {
                g[k][0] = a[k][0]; g[k][1] = a[k][1]; g[k][2] = a[k][2];
            }
        } else {
            load3<IN_SOA>(vin, b, r0i[k], scale, g[k]);
        }
    }
    // --- stage 3: v1 = a + g ; r1 = clamp(round(p + v1)) ---
    float v1[K][3];
    int r1d[K], r1h[K], r1w[K], r1i[K];
#pragma unroll
    for (int k = 0; k < K; ++k) {
        v1[k][0] = a[k][0] + g[k][0];
        v1[k][1] = a[k][1] + g[k][1];
        v1[k][2] = a[k][2] + g[k][2];
        clamp_idx(d, h[k], w[k], v1[k][0], v1[k][1], v1[k][2],
                  r1d[k], r1h[k], r1w[k], r1i[k]);
    }
    // --- stage 4: bb = v(r1), unmasked (never wave-skippable) ---
    float bb[K][3];
#pragma unroll
    for (int k = 0; k < K; ++k)
        load3<IN_SOA>(vin, b, r1i[k], scale, bb[k]);
    // --- stage 5: r2 = clamp(round(r1 + bb)) ; h2 = v(r2) ---
    int r2i[K];
#pragma unroll
    for (int k = 0; k < K; ++k) {
        int rd, rh, rw;
        clamp_idx(r1d[k], r1h[k], r1w[k], bb[k][0], bb[k][1], bb[k][2],
                  rd, rh, rw, r2i[k]);
    }
    float h2[K][3];
#pragma unroll
    for (int k = 0; k < K; ++k) {
        if constexpr (M2) {
            if (r2i[k] != r1i[k]) {
                load3<IN_SOA>(vin, b, r2i[k], scale, h2[k]);
            } else {
                h2[k][0] = bb[k][0]; h2[k][1] = bb[k][1]; h2[k][2] = bb[k][2];
            }
        } else {
            load3<IN_SOA>(vin, b, r2i[k], scale, h2[k]);
        }
    }
    // --- stage 6: out = v1 + (bb + h2)   [= v'(p) + v'(r1), ref grouping] ---
#pragma unroll
    for (int k = 0; k < K; ++k) {
        float o0 = v1[k][0] + (bb[k][0] + h2[k][0]);
        float o1 = v1[k][1] + (bb[k][1] + h2[k][1]);
        float o2 = v1[k][2] + (bb[k][2] + h2[k][2]);
        if constexpr (OUT_SOA) {
            int s = b * 3 * S + p[k];
            vout[s] = o0; vout[s + S] = o1; vout[s + 2 * S] = o2;
        } else {
            f3 v{o0, o1, o2};
            *(f3*)(vout + (b * S + p[k]) * 3) = v;
        }
    }
}

extern "C" void kernel_launch(void* const* d_in, const int* in_sizes, int n_in,
                              void* d_out, int out_size, void* d_ws, size_t ws_size,
                              hipStream_t stream) {
    const float* x = (const float*)d_in[0];
    float* out = (float*)d_out;     // 78,643,200 bytes — doubles as AoS intermediate
    float* ws  = (float*)d_ws;      // >= 78,643,200 bytes (tight AoS)

    // {2,2,2}: bytes-optimal schedule. Masks only where waves actually skip
    // (kernel 1's two sigma=0.125 sites); all other masks are pure overhead.
    fused2_k<true,  false, true,  true ><<<NT, 256, 0, stream>>>(x,   out, 1.0f / 64.0f); // steps 1-2
    fused2_k<false, false, false, false><<<NT, 256, 0, stream>>>(out, ws,  1.0f);         // steps 3-4
    fused2_k<false, true,  false, false><<<NT, 256, 0, stream>>>(ws,  out, 1.0f);         // steps 5-6
}